// Round 5
// baseline (876.331 us; speedup 1.0000x reference)
//
#include <hip/hip_runtime.h>
#include <math.h>

#define PAIRS 512
#define MAXN 192

// ---------------- offsets: exclusive prefix sums of len_s / len_t (shfl scan) ----------------
__global__ void offsets_kernel(const int* __restrict__ ls, const int* __restrict__ lt,
                               int* __restrict__ off) {
    __shared__ int wa[8], wb[8];
    int t = threadIdx.x;  // 512
    int a = ls[t], b = lt[t];
    int ia = a, ib = b;
#pragma unroll
    for (int d = 1; d < 64; d <<= 1) {
        int xa = __shfl_up(ia, d, 64);
        int xb = __shfl_up(ib, d, 64);
        if ((t & 63) >= d) { ia += xa; ib += xb; }
    }
    if ((t & 63) == 63) { wa[t >> 6] = ia; wb[t >> 6] = ib; }
    __syncthreads();
    int pa = 0, pb = 0;
    for (int w = 0; w < (t >> 6); w++) { pa += wa[w]; pb += wb[w]; }
    off[t] = pa + ia - a;          // exclusive
    off[PAIRS + t] = pb + ib - b;
}

// ================= CSR build over combined row space [0,Ns) ∪ [Ns,Ns+Nt) =================
__global__ __launch_bounds__(256) void count2_kernel(const int* __restrict__ eiS,
                                                     const int* __restrict__ eiT,
                                                     int* __restrict__ cnt,
                                                     int Es, int Et, int split) {
    int e = blockIdx.x * 256 + threadIdx.x;
    if (e < Es) atomicAdd(&cnt[eiS[Es + e]], 1);
    else if (e < Es + Et) atomicAdd(&cnt[split + eiT[Et + (e - Es)]], 1);
}

// single-block exclusive scan over N ints (N ≤ ~1M): per-thread chunk + shfl/LDS block scan
__global__ __launch_bounds__(1024) void scan_all_kernel(int* __restrict__ data,
                                                        int* __restrict__ cursor, int N) {
    __shared__ int wsums[16];
    int t = threadIdx.x;
    int per = (N + 1023) >> 10;
    int lo = t * per; if (lo > N) lo = N;
    int hi = lo + per; if (hi > N) hi = N;
    int s = 0;
    for (int i = lo; i < hi; i++) s += data[i];
    int inc = s;
#pragma unroll
    for (int d = 1; d < 64; d <<= 1) {
        int x = __shfl_up(inc, d, 64);
        if ((t & 63) >= d) inc += x;
    }
    if ((t & 63) == 63) wsums[t >> 6] = inc;
    __syncthreads();
    int base = 0;
    for (int q = 0; q < (t >> 6); q++) base += wsums[q];
    int excl = base + inc - s;
    for (int i = lo; i < hi; i++) {
        int v = data[i];
        data[i] = excl;
        cursor[i] = excl;
        excl += v;
    }
}

__global__ __launch_bounds__(256) void fill2_kernel(const int* __restrict__ eiS,
                                                    const int* __restrict__ eiT,
                                                    int* __restrict__ cursor,
                                                    int* __restrict__ src,
                                                    int Es, int Et, int split) {
    int e = blockIdx.x * 256 + threadIdx.x;
    if (e < Es) {
        int p = atomicAdd(&cursor[eiS[Es + e]], 1);
        src[p] = eiS[e];
    } else if (e < Es + Et) {
        int ee = e - Es;
        int p = atomicAdd(&cursor[split + eiT[Et + ee]], 1);
        src[p] = eiT[ee];
    }
}

// ================= gather aggregation (combined rows) =================
template <int F>
__global__ __launch_bounds__(256) void gather_kernel(const float* __restrict__ featA,
                                                     const float* __restrict__ featB,
                                                     int split,
                                                     const int* __restrict__ rs,
                                                     const int* __restrict__ re,
                                                     const int* __restrict__ src,
                                                     float* __restrict__ agg, int N) {
    int gid = blockIdx.x * 256 + threadIdx.x;
    int row = gid / F;
    int lane = threadIdx.x & (F - 1);
    if (row >= N) return;
    int b = rs[row], e = re[row];
    int cnt = e - b;
    const float* feat = (row < split) ? featA : featB;
    int pre = cnt < F ? cnt : F;
    int sidx = (lane < cnt) ? src[b + lane] : 0;
    float acc = 0.f;
    for (int q = 0; q < pre; q++) {
        int s = __shfl(sidx, q, F);
        acc += feat[(size_t)s * F + lane];
    }
    for (int q = b + F; q < e; q++) acc += feat[(size_t)src[q] * F + lane];
    agg[(size_t)row * F + lane] = acc;
}

// ================= tiled dense GEMMs: 64 rows × 64 outs / block, K-chunk ≤ 64 =================
template <int KIN>
__global__ __launch_bounds__(256) void lin_gemm_kernel(const float* __restrict__ agg,
    const float* __restrict__ hinA, const float* __restrict__ hinB, int split,
    const float* __restrict__ Wrel, const float* __restrict__ brel,
    const float* __restrict__ Wroot, float* __restrict__ hout, int N) {
    __shared__ float Abuf[64 * 65];
    __shared__ float4 Wbuf[64 * 16];
    int tid = threadIdx.x;
    int i = tid & 15, j = tid >> 4;
    int rowbase = blockIdx.x * 64;
    float4 bv = ((const float4*)brel)[j];
    float acc[4][4];
#pragma unroll
    for (int r = 0; r < 4; r++) { acc[r][0] = bv.x; acc[r][1] = bv.y; acc[r][2] = bv.z; acc[r][3] = bv.w; }

    for (int c0 = 0; c0 < 2 * KIN; c0 += 64) {
        __syncthreads();
        for (int t = tid; t < 1024; t += 256) {
            int r = t >> 4, k4 = t & 15;
            int kg = c0 + 4 * k4;
            int row = rowbase + r; if (row >= N) row = N - 1;
            float4 v;
            if (kg < KIN) {
                v = ((const float4*)(agg + (size_t)row * KIN))[kg >> 2];
            } else {
                int kk = kg - KIN;
                const float* h = (row < split) ? hinA + (size_t)row * KIN
                                               : hinB + (size_t)(row - split) * KIN;
                v = ((const float4*)h)[kk >> 2];
            }
            float* d = Abuf + r * 65 + 4 * k4;
            d[0] = v.x; d[1] = v.y; d[2] = v.z; d[3] = v.w;
        }
        for (int t = tid; t < 1024; t += 256) {
            int k = t >> 4, jj = t & 15;
            int kg = c0 + k;
            const float* Wsrc = (kg < KIN) ? (Wrel + (size_t)kg * 64)
                                           : (Wroot + (size_t)(kg - KIN) * 64);
            Wbuf[t] = ((const float4*)Wsrc)[jj];
        }
        __syncthreads();
#pragma unroll 4
        for (int k = 0; k < 64; k++) {
            float4 wv = Wbuf[k * 16 + j];
            float a0 = Abuf[(4 * i + 0) * 65 + k];
            float a1 = Abuf[(4 * i + 1) * 65 + k];
            float a2 = Abuf[(4 * i + 2) * 65 + k];
            float a3 = Abuf[(4 * i + 3) * 65 + k];
            acc[0][0] = fmaf(a0, wv.x, acc[0][0]); acc[0][1] = fmaf(a0, wv.y, acc[0][1]);
            acc[0][2] = fmaf(a0, wv.z, acc[0][2]); acc[0][3] = fmaf(a0, wv.w, acc[0][3]);
            acc[1][0] = fmaf(a1, wv.x, acc[1][0]); acc[1][1] = fmaf(a1, wv.y, acc[1][1]);
            acc[1][2] = fmaf(a1, wv.z, acc[1][2]); acc[1][3] = fmaf(a1, wv.w, acc[1][3]);
            acc[2][0] = fmaf(a2, wv.x, acc[2][0]); acc[2][1] = fmaf(a2, wv.y, acc[2][1]);
            acc[2][2] = fmaf(a2, wv.z, acc[2][2]); acc[2][3] = fmaf(a2, wv.w, acc[2][3]);
            acc[3][0] = fmaf(a3, wv.x, acc[3][0]); acc[3][1] = fmaf(a3, wv.y, acc[3][1]);
            acc[3][2] = fmaf(a3, wv.z, acc[3][2]); acc[3][3] = fmaf(a3, wv.w, acc[3][3]);
        }
    }
#pragma unroll
    for (int r = 0; r < 4; r++) {
        int row = rowbase + 4 * i + r;
        if (row < N) {
            float4 o = make_float4(fmaxf(acc[r][0], 0.f), fmaxf(acc[r][1], 0.f),
                                   fmaxf(acc[r][2], 0.f), fmaxf(acc[r][3], 0.f));
            ((float4*)(hout + (size_t)row * 64))[j] = o;
        }
    }
}

__global__ __launch_bounds__(256) void emb_gemm_kernel(const float* __restrict__ xA,
    const float* __restrict__ xB, int split,
    const float* __restrict__ h1, const float* __restrict__ h2,
    const float* __restrict__ We, const float* __restrict__ be,
    float* __restrict__ emb, int N) {
    __shared__ float Abuf[64 * 65];
    __shared__ float4 Wbuf[64 * 16];
    int tid = threadIdx.x;
    int i = tid & 15, j = tid >> 4;
    int rowbase = blockIdx.x * 64;
    float4 bv = ((const float4*)be)[j];
    float acc[4][4];
#pragma unroll
    for (int r = 0; r < 4; r++) { acc[r][0] = bv.x; acc[r][1] = bv.y; acc[r][2] = bv.z; acc[r][3] = bv.w; }

    for (int c0 = 0; c0 < 160; c0 += 64) {
        int kw = (160 - c0 < 64) ? (160 - c0) : 64;
        int sh = (kw == 64) ? 4 : 3;
        int msk = (1 << sh) - 1;
        __syncthreads();
        for (int t = tid; t < 64 * (kw >> 2); t += 256) {
            int r = t >> sh, k4 = t & msk;
            int kg = c0 + 4 * k4;
            int row = rowbase + r; if (row >= N) row = N - 1;
            float4 v;
            if (kg < 32) {
                const float* x = (row < split) ? xA + (size_t)row * 32
                                               : xB + (size_t)(row - split) * 32;
                v = ((const float4*)x)[kg >> 2];
            } else if (kg < 96) {
                v = ((const float4*)(h1 + (size_t)row * 64))[(kg - 32) >> 2];
            } else {
                v = ((const float4*)(h2 + (size_t)row * 64))[(kg - 96) >> 2];
            }
            float* d = Abuf + r * 65 + 4 * k4;
            d[0] = v.x; d[1] = v.y; d[2] = v.z; d[3] = v.w;
        }
        for (int t = tid; t < kw * 16; t += 256) {
            int k = t >> 4, jj = t & 15;
            Wbuf[t] = ((const float4*)(We + (size_t)(c0 + k) * 64))[jj];
        }
        __syncthreads();
#pragma unroll 4
        for (int k = 0; k < kw; k++) {
            float4 wv = Wbuf[k * 16 + j];
            float a0 = Abuf[(4 * i + 0) * 65 + k];
            float a1 = Abuf[(4 * i + 1) * 65 + k];
            float a2 = Abuf[(4 * i + 2) * 65 + k];
            float a3 = Abuf[(4 * i + 3) * 65 + k];
            acc[0][0] = fmaf(a0, wv.x, acc[0][0]); acc[0][1] = fmaf(a0, wv.y, acc[0][1]);
            acc[0][2] = fmaf(a0, wv.z, acc[0][2]); acc[0][3] = fmaf(a0, wv.w, acc[0][3]);
            acc[1][0] = fmaf(a1, wv.x, acc[1][0]); acc[1][1] = fmaf(a1, wv.y, acc[1][1]);
            acc[1][2] = fmaf(a1, wv.z, acc[1][2]); acc[1][3] = fmaf(a1, wv.w, acc[1][3]);
            acc[2][0] = fmaf(a2, wv.x, acc[2][0]); acc[2][1] = fmaf(a2, wv.y, acc[2][1]);
            acc[2][2] = fmaf(a2, wv.z, acc[2][2]); acc[2][3] = fmaf(a2, wv.w, acc[2][3]);
            acc[3][0] = fmaf(a3, wv.x, acc[3][0]); acc[3][1] = fmaf(a3, wv.y, acc[3][1]);
            acc[3][2] = fmaf(a3, wv.z, acc[3][2]); acc[3][3] = fmaf(a3, wv.w, acc[3][3]);
        }
    }
    __syncthreads();
#pragma unroll
    for (int r = 0; r < 4; r++)
#pragma unroll
        for (int c = 0; c < 4; c++)
            Abuf[(4 * i + r) * 65 + 4 * j + c] = acc[r][c];
    __syncthreads();
    int lane = tid & 63, wv = tid >> 6;
    for (int rr = 0; rr < 16; rr++) {
        int r = wv * 16 + rr;
        float val = Abuf[r * 65 + lane];
        float ss = val * val;
#pragma unroll
        for (int d = 32; d > 0; d >>= 1) ss += __shfl_xor(ss, d, 64);
        int row = rowbase + r;
        if (row < N) emb[(size_t)row * 64 + lane] = val / fmaxf(sqrtf(ss), 1e-12f);
    }
}

// ========== fused cost + Sinkhorn + gamma + geds2: one block (1024 thr) per pair ==========
// thread (ti,tj) = (tid&31, tid>>5) owns rows 6ti..+5, cols 6tj..+5; K tile in VGPRs.
__global__ __launch_bounds__(1024, 1) void cost_sink_kernel(const float* __restrict__ embS,
                                                            const float* __restrict__ embT,
                                                            const float* __restrict__ vraw,
                                                            const int* __restrict__ lenS,
                                                            const int* __restrict__ lenT,
                                                            const int* __restrict__ off,
                                                            float* __restrict__ cost,
                                                            float* __restrict__ gamma,
                                                            float* __restrict__ geds2,
                                                            int Ns) {
    __shared__ float sST[24960];      // sS[192*65] | sT[192*65]; later reused as 96*193 bounce
    __shared__ float part[32 * 193];  // matvec partials
    __shared__ float u[MAXN];
    __shared__ float v[MAXN];
    __shared__ float sqS[MAXN];
    __shared__ float sqT[MAXN];
    __shared__ __align__(16) float virt[64];
    __shared__ float wsum[16];

    int p = blockIdx.x;
    int tid = threadIdx.x;
    int ti = tid & 31, tj = tid >> 5;
    int n = lenS[p], m = lenT[p];
    int offs = off[p], offt = off[PAIRS + p];
    float* sS = sST;
    float* sT = sST + 12480;

    if (tid < 64) {
        float vv = vraw[tid];
        float ss = vv * vv;
#pragma unroll
        for (int d = 32; d > 0; d >>= 1) ss += __shfl_xor(ss, d, 64);
        virt[tid] = vv / fmaxf(sqrtf(ss), 1e-12f);
    }
    __syncthreads();

    // stage embeddings: 192 rows x 16 float4 each (3 per thread)
    for (int t = tid; t < 192 * 16; t += 1024) {
        int r = t >> 4, q = t & 15;
        int gi = offs + r; if (gi > Ns - 1) gi = Ns - 1;
        float4 vv = ((const float4*)embS)[(size_t)gi * 16 + q];
        float* d = sS + r * 65 + q * 4;
        d[0] = vv.x; d[1] = vv.y; d[2] = vv.z; d[3] = vv.w;
    }
    for (int t = tid; t < 192 * 16; t += 1024) {
        int j = t >> 4, q = t & 15;
        float4 vv;
        if (j < m) vv = ((const float4*)embT)[(size_t)(offt + j) * 16 + q];
        else       vv = ((const float4*)virt)[q];
        float* d = sT + j * 65 + q * 4;
        d[0] = vv.x; d[1] = vv.y; d[2] = vv.z; d[3] = vv.w;
    }
    __syncthreads();

    if (tid < 192) {
        float s = 0.f;
#pragma unroll
        for (int k = 0; k < 64; k++) { float a = sS[tid * 65 + k]; s = fmaf(a, a, s); }
        sqS[tid] = s;
    } else if (tid < 384) {
        int j = tid - 192;
        float s = 0.f;
#pragma unroll
        for (int k = 0; k < 64; k++) { float a = sT[j * 65 + k]; s = fmaf(a, a, s); }
        sqT[j] = s;
    }
    __syncthreads();

    // ---- phase A: 6x6 cost tile in registers ----
    float kt[6][6];   // dot, then cost, then K
#pragma unroll
    for (int r = 0; r < 6; r++)
#pragma unroll
        for (int c = 0; c < 6; c++) kt[r][c] = 0.f;

    int ib = ti * 6, jb = tj * 6;
    for (int k = 0; k < 64; k++) {
        float sv[6], tv[6];
#pragma unroll
        for (int r = 0; r < 6; r++) sv[r] = sS[(ib + r) * 65 + k];
#pragma unroll
        for (int c = 0; c < 6; c++) tv[c] = sT[(jb + c) * 65 + k];
#pragma unroll
        for (int r = 0; r < 6; r++)
#pragma unroll
            for (int c = 0; c < 6; c++) kt[r][c] = fmaf(sv[r], tv[c], kt[r][c]);
    }
#pragma unroll
    for (int r = 0; r < 6; r++) {
        int i = ib + r;
        bool rv = i < n;
        float sqi = sqS[i];
#pragma unroll
        for (int c = 0; c < 6; c++) {
            int j = jb + c;
            float cd = sqrtf(fmaxf(sqi + sqT[j] - 2.f * kt[r][c], 1e-12f));
            bool cv = j < n;
            kt[r][c] = (rv && cv) ? cd : ((!rv && !cv) ? 0.f : 1000.f);
        }
    }

    // ---- write cost via LDS bounce (2 row-halves), fully coalesced HBM stores ----
    float* bounce = sST;  // 96*193 floats, embeddings dead now
    float* cp = cost + (size_t)p * MAXN * MAXN;
    for (int h = 0; h < 2; h++) {
        __syncthreads();
        if ((ti >> 4) == h) {
            int rb = ib - 96 * h;
#pragma unroll
            for (int r = 0; r < 6; r++)
#pragma unroll
                for (int c = 0; c < 6; c++)
                    bounce[(rb + r) * 193 + jb + c] = kt[r][c];
        }
        __syncthreads();
        for (int q = 0; q < 18; q++) {
            int el = q * 1024 + tid;
            int row = el / 192, col = el - row * 192;
            cp[(size_t)(96 * h + row) * 192 + col] = bounce[row * 193 + col];
        }
    }

    // ---- K = exp(-10*cost) in registers ----
#pragma unroll
    for (int r = 0; r < 6; r++)
#pragma unroll
        for (int c = 0; c < 6; c++) kt[r][c] = expf(-10.f * kt[r][c]);

    if (tid < MAXN) u[tid] = 1.f / 192.f;

    // ---- 8 Sinkhorn iterations, partials through part[] ----
    for (int it = 0; it < 8; it++) {
        __syncthreads();
        {
            float ur[6];
#pragma unroll
            for (int r = 0; r < 6; r++) ur[r] = u[ib + r];
#pragma unroll
            for (int c = 0; c < 6; c++) {
                float s = 0.f;
#pragma unroll
                for (int r = 0; r < 6; r++) s = fmaf(kt[r][c], ur[r], s);
                part[ti * 193 + jb + c] = s;
            }
        }
        __syncthreads();
        if (tid < MAXN) {
            float s = 0.f;
#pragma unroll
            for (int q = 0; q < 32; q++) s += part[q * 193 + tid];
            v[tid] = 1.f / s;
        }
        __syncthreads();
        {
            float vc[6];
#pragma unroll
            for (int c = 0; c < 6; c++) vc[c] = v[jb + c];
#pragma unroll
            for (int r = 0; r < 6; r++) {
                float s = 0.f;
#pragma unroll
                for (int c = 0; c < 6; c++) s = fmaf(kt[r][c], vc[c], s);
                part[tj * 193 + ib + r] = s;
            }
        }
        __syncthreads();
        if (tid < MAXN) {
            float s = 0.f;
#pragma unroll
            for (int q = 0; q < 32; q++) s += part[q * 193 + tid];
            u[tid] = 1.f / s;
        }
    }
    __syncthreads();

    // ---- gamma + geds (cost recovered as -0.1*log K; K==0 contributes 0) ----
    float ur[6], vc[6];
#pragma unroll
    for (int r = 0; r < 6; r++) ur[r] = u[ib + r];
#pragma unroll
    for (int c = 0; c < 6; c++) vc[c] = v[jb + c];

    float acc = 0.f;
#pragma unroll
    for (int r = 0; r < 6; r++)
#pragma unroll
        for (int c = 0; c < 6; c++) {
            float kk = kt[r][c];
            float g = ur[r] * kk * vc[c];
            if (kk > 0.f) acc = fmaf(g, -0.1f * logf(kk), acc);
        }
#pragma unroll
    for (int d = 32; d > 0; d >>= 1) acc += __shfl_xor(acc, d, 64);
    if ((tid & 63) == 0) wsum[tid >> 6] = acc;

    float* gp = gamma + (size_t)p * MAXN * MAXN;
    for (int h = 0; h < 2; h++) {
        __syncthreads();
        if ((ti >> 4) == h) {
            int rb = ib - 96 * h;
#pragma unroll
            for (int r = 0; r < 6; r++)
#pragma unroll
                for (int c = 0; c < 6; c++)
                    bounce[(rb + r) * 193 + jb + c] = ur[r] * kt[r][c] * vc[c];
        }
        __syncthreads();
        for (int q = 0; q < 18; q++) {
            int el = q * 1024 + tid;
            int row = el / 192, col = el - row * 192;
            gp[(size_t)(96 * h + row) * 192 + col] = bounce[row * 193 + col];
        }
    }
    if (tid == 0) {
        float s = 0.f;
        for (int q = 0; q < 16; q++) s += wsum[q];
        geds2[p] = s / (float)(n + m);
    }
}

extern "C" void kernel_launch(void* const* d_in, const int* in_sizes, int n_in,
                              void* d_out, int out_size, void* d_ws, size_t ws_size,
                              hipStream_t stream) {
    const float* x_s     = (const float*)d_in[0];
    const float* x_t     = (const float*)d_in[1];
    const float* W_rel0  = (const float*)d_in[2];
    const float* b_rel0  = (const float*)d_in[3];
    const float* W_root0 = (const float*)d_in[4];
    const float* W_rel1  = (const float*)d_in[5];
    const float* b_rel1  = (const float*)d_in[6];
    const float* W_root1 = (const float*)d_in[7];
    const float* W_e     = (const float*)d_in[8];
    const float* b_e     = (const float*)d_in[9];
    const float* virt    = (const float*)d_in[10];
    const int*   ei_s    = (const int*)d_in[11];
    const int*   ei_t    = (const int*)d_in[12];
    const int*   len_s   = (const int*)d_in[13];
    const int*   len_t   = (const int*)d_in[14];

    int Ns = in_sizes[0] / 32;
    int Nt = in_sizes[1] / 32;
    int Es = in_sizes[11] / 2;
    int Et = in_sizes[12] / 2;
    int Ntot = Ns + Nt;
    int Etot = Es + Et;

    // ---- workspace layout ----
    char* w = (char*)d_ws;
    int* off  = (int*)w;              w += 1024 * 4;
    int* rs   = (int*)w;              w += (size_t)Ntot * 4;
    int* cur  = (int*)w;              w += (size_t)Ntot * 4;
    int* src  = (int*)w;              w += (size_t)Etot * 4;
    w = (char*)(((size_t)w + 255) & ~(size_t)255);
    float* agg = (float*)w;           w += (size_t)Ntot * 64 * 4;  // gather out; later emb
    float* h1  = (float*)w;           w += (size_t)Ntot * 64 * 4;
    float* h2  = (float*)w;           w += (size_t)Ntot * 64 * 4;

    float* out_gamma = (float*)d_out;
    float* out_cost  = out_gamma + (size_t)PAIRS * MAXN * MAXN;
    float* out_geds  = out_cost + (size_t)PAIRS * MAXN * MAXN;

    offsets_kernel<<<1, PAIRS, 0, stream>>>(len_s, len_t, off);

    // ---- combined CSR build ----
    hipMemsetAsync(rs, 0, (size_t)Ntot * 4, stream);
    count2_kernel<<<(Etot + 255) / 256, 256, 0, stream>>>(ei_s, ei_t, rs, Es, Et, Ns);
    scan_all_kernel<<<1, 1024, 0, stream>>>(rs, cur, Ntot);
    fill2_kernel<<<(Etot + 255) / 256, 256, 0, stream>>>(ei_s, ei_t, cur, src, Es, Et, Ns);

    int gblk = (Ntot + 63) / 64;

    // ---- combined GNN ----
    gather_kernel<32><<<(int)(((long long)Ntot * 32 + 255) / 256), 256, 0, stream>>>(
        x_s, x_t, Ns, rs, cur, src, agg, Ntot);
    lin_gemm_kernel<32><<<gblk, 256, 0, stream>>>(
        agg, x_s, x_t, Ns, W_rel0, b_rel0, W_root0, h1, Ntot);
    gather_kernel<64><<<(int)(((long long)Ntot * 64 + 255) / 256), 256, 0, stream>>>(
        h1, h1 + (size_t)Ns * 64, Ns, rs, cur, src, agg, Ntot);   // fixed: featB = T block of h1
    lin_gemm_kernel<64><<<gblk, 256, 0, stream>>>(
        agg, h1, h1, Ntot + 1, W_rel1, b_rel1, W_root1, h2, Ntot);  // h1 combined: split never hit
    emb_gemm_kernel<<<gblk, 256, 0, stream>>>(
        x_s, x_t, Ns, h1, h2, W_e, b_e, agg, Ntot);  // emb -> agg (S rows then T rows)

    // ---- fused cost + sinkhorn ----
    cost_sink_kernel<<<PAIRS, 1024, 0, stream>>>(
        agg, agg + (size_t)Ns * 64, virt, len_s, len_t, off,
        out_cost, out_gamma, out_geds, Ns);
}

// Round 6
// 651.103 us; speedup vs baseline: 1.3459x; 1.3459x over previous
//
#include <hip/hip_runtime.h>
#include <math.h>

#define PAIRS 512
#define MAXN 192

// ---------------- offsets: exclusive prefix sums of len_s / len_t (shfl scan) ----------------
__global__ void offsets_kernel(const int* __restrict__ ls, const int* __restrict__ lt,
                               int* __restrict__ off) {
    __shared__ int wa[8], wb[8];
    int t = threadIdx.x;  // 512
    int a = ls[t], b = lt[t];
    int ia = a, ib = b;
#pragma unroll
    for (int d = 1; d < 64; d <<= 1) {
        int xa = __shfl_up(ia, d, 64);
        int xb = __shfl_up(ib, d, 64);
        if ((t & 63) >= d) { ia += xa; ib += xb; }
    }
    if ((t & 63) == 63) { wa[t >> 6] = ia; wb[t >> 6] = ib; }
    __syncthreads();
    int pa = 0, pb = 0;
    for (int w = 0; w < (t >> 6); w++) { pa += wa[w]; pb += wb[w]; }
    off[t] = pa + ia - a;          // exclusive
    off[PAIRS + t] = pb + ib - b;
}

// ================= CSR build over combined row space [0,Ns) ∪ [Ns,Ns+Nt) =================
__global__ __launch_bounds__(256) void count2_kernel(const int* __restrict__ eiS,
                                                     const int* __restrict__ eiT,
                                                     int* __restrict__ cnt,
                                                     int Es, int Et, int split) {
    int e = blockIdx.x * 256 + threadIdx.x;
    if (e < Es) atomicAdd(&cnt[eiS[Es + e]], 1);
    else if (e < Es + Et) atomicAdd(&cnt[split + eiT[Et + (e - Es)]], 1);
}

// multi-block scan: scan1 (1024 ints/block) -> scan2 (block sums) -> scan3 (apply)
__global__ __launch_bounds__(256) void scan1_kernel(int* __restrict__ data,
                                                    int* __restrict__ blockSums, int N) {
    __shared__ int sc[256];
    int t = threadIdx.x;
    int base = blockIdx.x * 1024;
    int v[4];
    int s = 0;
#pragma unroll
    for (int q = 0; q < 4; q++) {
        int i = base + t * 4 + q;
        v[q] = (i < N) ? data[i] : 0;
        s += v[q];
    }
    sc[t] = s;
    __syncthreads();
    for (int d = 1; d < 256; d <<= 1) {
        int x = (t >= d) ? sc[t - d] : 0;
        __syncthreads();
        sc[t] += x;
        __syncthreads();
    }
    int excl = sc[t] - s;
#pragma unroll
    for (int q = 0; q < 4; q++) {
        int i = base + t * 4 + q;
        if (i < N) { data[i] = excl; excl += v[q]; }
    }
    if (t == 255) blockSums[blockIdx.x] = sc[255];
}

__global__ void scan2_kernel(int* __restrict__ blockSums, int B) {
    __shared__ int sh[256];
    int t = threadIdx.x;  // 256
    int v = (t < B) ? blockSums[t] : 0;
    sh[t] = v;
    __syncthreads();
    for (int d = 1; d < 256; d <<= 1) {
        int x = (t >= d) ? sh[t - d] : 0;
        __syncthreads();
        sh[t] += x;
        __syncthreads();
    }
    if (t < B) blockSums[t] = sh[t] - v;
}

__global__ __launch_bounds__(256) void scan3_kernel(int* __restrict__ data,
                                                    const int* __restrict__ blockSums,
                                                    int* __restrict__ cursor, int N) {
    int i = blockIdx.x * 256 + threadIdx.x;
    if (i < N) {
        int v = data[i] + blockSums[i >> 10];
        data[i] = v;
        cursor[i] = v;
    }
}

__global__ __launch_bounds__(256) void fill2_kernel(const int* __restrict__ eiS,
                                                    const int* __restrict__ eiT,
                                                    int* __restrict__ cursor,
                                                    int* __restrict__ src,
                                                    int Es, int Et, int split) {
    int e = blockIdx.x * 256 + threadIdx.x;
    if (e < Es) {
        int p = atomicAdd(&cursor[eiS[Es + e]], 1);
        src[p] = eiS[e];
    } else if (e < Es + Et) {
        int ee = e - Es;
        int p = atomicAdd(&cursor[split + eiT[Et + ee]], 1);
        src[p] = eiT[ee];
    }
}

// ================= gather aggregation (combined rows) =================
template <int F>
__global__ __launch_bounds__(256) void gather_kernel(const float* __restrict__ featA,
                                                     const float* __restrict__ featB,
                                                     int split,
                                                     const int* __restrict__ rs,
                                                     const int* __restrict__ re,
                                                     const int* __restrict__ src,
                                                     float* __restrict__ agg, int N) {
    int gid = blockIdx.x * 256 + threadIdx.x;
    int row = gid / F;
    int lane = threadIdx.x & (F - 1);
    if (row >= N) return;
    int b = rs[row], e = re[row];
    int cnt = e - b;
    const float* feat = (row < split) ? featA : featB;
    int pre = cnt < F ? cnt : F;
    int sidx = (lane < cnt) ? src[b + lane] : 0;
    float acc = 0.f;
    for (int q = 0; q < pre; q++) {
        int s = __shfl(sidx, q, F);
        acc += feat[(size_t)s * F + lane];
    }
    for (int q = b + F; q < e; q++) acc += feat[(size_t)src[q] * F + lane];
    agg[(size_t)row * F + lane] = acc;
}

// ================= tiled dense GEMMs: 64 rows × 64 outs / block, K-chunk ≤ 64 =================
template <int KIN>
__global__ __launch_bounds__(256) void lin_gemm_kernel(const float* __restrict__ agg,
    const float* __restrict__ hinA, const float* __restrict__ hinB, int split,
    const float* __restrict__ Wrel, const float* __restrict__ brel,
    const float* __restrict__ Wroot, float* __restrict__ hout, int N) {
    __shared__ float Abuf[64 * 65];
    __shared__ float4 Wbuf[64 * 16];
    int tid = threadIdx.x;
    int i = tid & 15, j = tid >> 4;
    int rowbase = blockIdx.x * 64;
    float4 bv = ((const float4*)brel)[j];
    float acc[4][4];
#pragma unroll
    for (int r = 0; r < 4; r++) { acc[r][0] = bv.x; acc[r][1] = bv.y; acc[r][2] = bv.z; acc[r][3] = bv.w; }

    for (int c0 = 0; c0 < 2 * KIN; c0 += 64) {
        __syncthreads();
        for (int t = tid; t < 1024; t += 256) {
            int r = t >> 4, k4 = t & 15;
            int kg = c0 + 4 * k4;
            int row = rowbase + r; if (row >= N) row = N - 1;
            float4 v;
            if (kg < KIN) {
                v = ((const float4*)(agg + (size_t)row * KIN))[kg >> 2];
            } else {
                int kk = kg - KIN;
                const float* h = (row < split) ? hinA + (size_t)row * KIN
                                               : hinB + (size_t)(row - split) * KIN;
                v = ((const float4*)h)[kk >> 2];
            }
            float* d = Abuf + r * 65 + 4 * k4;
            d[0] = v.x; d[1] = v.y; d[2] = v.z; d[3] = v.w;
        }
        for (int t = tid; t < 1024; t += 256) {
            int k = t >> 4, jj = t & 15;
            int kg = c0 + k;
            const float* Wsrc = (kg < KIN) ? (Wrel + (size_t)kg * 64)
                                           : (Wroot + (size_t)(kg - KIN) * 64);
            Wbuf[t] = ((const float4*)Wsrc)[jj];
        }
        __syncthreads();
#pragma unroll 4
        for (int k = 0; k < 64; k++) {
            float4 wv = Wbuf[k * 16 + j];
            float a0 = Abuf[(4 * i + 0) * 65 + k];
            float a1 = Abuf[(4 * i + 1) * 65 + k];
            float a2 = Abuf[(4 * i + 2) * 65 + k];
            float a3 = Abuf[(4 * i + 3) * 65 + k];
            acc[0][0] = fmaf(a0, wv.x, acc[0][0]); acc[0][1] = fmaf(a0, wv.y, acc[0][1]);
            acc[0][2] = fmaf(a0, wv.z, acc[0][2]); acc[0][3] = fmaf(a0, wv.w, acc[0][3]);
            acc[1][0] = fmaf(a1, wv.x, acc[1][0]); acc[1][1] = fmaf(a1, wv.y, acc[1][1]);
            acc[1][2] = fmaf(a1, wv.z, acc[1][2]); acc[1][3] = fmaf(a1, wv.w, acc[1][3]);
            acc[2][0] = fmaf(a2, wv.x, acc[2][0]); acc[2][1] = fmaf(a2, wv.y, acc[2][1]);
            acc[2][2] = fmaf(a2, wv.z, acc[2][2]); acc[2][3] = fmaf(a2, wv.w, acc[2][3]);
            acc[3][0] = fmaf(a3, wv.x, acc[3][0]); acc[3][1] = fmaf(a3, wv.y, acc[3][1]);
            acc[3][2] = fmaf(a3, wv.z, acc[3][2]); acc[3][3] = fmaf(a3, wv.w, acc[3][3]);
        }
    }
#pragma unroll
    for (int r = 0; r < 4; r++) {
        int row = rowbase + 4 * i + r;
        if (row < N) {
            float4 o = make_float4(fmaxf(acc[r][0], 0.f), fmaxf(acc[r][1], 0.f),
                                   fmaxf(acc[r][2], 0.f), fmaxf(acc[r][3], 0.f));
            ((float4*)(hout + (size_t)row * 64))[j] = o;
        }
    }
}

__global__ __launch_bounds__(256) void emb_gemm_kernel(const float* __restrict__ xA,
    const float* __restrict__ xB, int split,
    const float* __restrict__ h1, const float* __restrict__ h2,
    const float* __restrict__ We, const float* __restrict__ be,
    float* __restrict__ emb, int N) {
    __shared__ float Abuf[64 * 65];
    __shared__ float4 Wbuf[64 * 16];
    int tid = threadIdx.x;
    int i = tid & 15, j = tid >> 4;
    int rowbase = blockIdx.x * 64;
    float4 bv = ((const float4*)be)[j];
    float acc[4][4];
#pragma unroll
    for (int r = 0; r < 4; r++) { acc[r][0] = bv.x; acc[r][1] = bv.y; acc[r][2] = bv.z; acc[r][3] = bv.w; }

    for (int c0 = 0; c0 < 160; c0 += 64) {
        int kw = (160 - c0 < 64) ? (160 - c0) : 64;
        int sh = (kw == 64) ? 4 : 3;
        int msk = (1 << sh) - 1;
        __syncthreads();
        for (int t = tid; t < 64 * (kw >> 2); t += 256) {
            int r = t >> sh, k4 = t & msk;
            int kg = c0 + 4 * k4;
            int row = rowbase + r; if (row >= N) row = N - 1;
            float4 v;
            if (kg < 32) {
                const float* x = (row < split) ? xA + (size_t)row * 32
                                               : xB + (size_t)(row - split) * 32;
                v = ((const float4*)x)[kg >> 2];
            } else if (kg < 96) {
                v = ((const float4*)(h1 + (size_t)row * 64))[(kg - 32) >> 2];
            } else {
                v = ((const float4*)(h2 + (size_t)row * 64))[(kg - 96) >> 2];
            }
            float* d = Abuf + r * 65 + 4 * k4;
            d[0] = v.x; d[1] = v.y; d[2] = v.z; d[3] = v.w;
        }
        for (int t = tid; t < kw * 16; t += 256) {
            int k = t >> 4, jj = t & 15;
            Wbuf[t] = ((const float4*)(We + (size_t)(c0 + k) * 64))[jj];
        }
        __syncthreads();
#pragma unroll 4
        for (int k = 0; k < kw; k++) {
            float4 wv = Wbuf[k * 16 + j];
            float a0 = Abuf[(4 * i + 0) * 65 + k];
            float a1 = Abuf[(4 * i + 1) * 65 + k];
            float a2 = Abuf[(4 * i + 2) * 65 + k];
            float a3 = Abuf[(4 * i + 3) * 65 + k];
            acc[0][0] = fmaf(a0, wv.x, acc[0][0]); acc[0][1] = fmaf(a0, wv.y, acc[0][1]);
            acc[0][2] = fmaf(a0, wv.z, acc[0][2]); acc[0][3] = fmaf(a0, wv.w, acc[0][3]);
            acc[1][0] = fmaf(a1, wv.x, acc[1][0]); acc[1][1] = fmaf(a1, wv.y, acc[1][1]);
            acc[1][2] = fmaf(a1, wv.z, acc[1][2]); acc[1][3] = fmaf(a1, wv.w, acc[1][3]);
            acc[2][0] = fmaf(a2, wv.x, acc[2][0]); acc[2][1] = fmaf(a2, wv.y, acc[2][1]);
            acc[2][2] = fmaf(a2, wv.z, acc[2][2]); acc[2][3] = fmaf(a2, wv.w, acc[2][3]);
            acc[3][0] = fmaf(a3, wv.x, acc[3][0]); acc[3][1] = fmaf(a3, wv.y, acc[3][1]);
            acc[3][2] = fmaf(a3, wv.z, acc[3][2]); acc[3][3] = fmaf(a3, wv.w, acc[3][3]);
        }
    }
    __syncthreads();
#pragma unroll
    for (int r = 0; r < 4; r++)
#pragma unroll
        for (int c = 0; c < 4; c++)
            Abuf[(4 * i + r) * 65 + 4 * j + c] = acc[r][c];
    __syncthreads();
    int lane = tid & 63, wv = tid >> 6;
    for (int rr = 0; rr < 16; rr++) {
        int r = wv * 16 + rr;
        float val = Abuf[r * 65 + lane];
        float ss = val * val;
#pragma unroll
        for (int d = 32; d > 0; d >>= 1) ss += __shfl_xor(ss, d, 64);
        int row = rowbase + r;
        if (row < N) emb[(size_t)row * 64 + lane] = val / fmaxf(sqrtf(ss), 1e-12f);
    }
}

// ========== fused cost + Sinkhorn + gamma + geds2: one block (1024 thr) per pair ==========
// thread (ti,tj) = (tid&31, tid>>5) owns rows 6ti..+5, cols 6tj..+5; K tile in VGPRs.
__global__ __launch_bounds__(1024, 1) void cost_sink_kernel(const float* __restrict__ embS,
                                                            const float* __restrict__ embT,
                                                            const float* __restrict__ vraw,
                                                            const int* __restrict__ lenS,
                                                            const int* __restrict__ lenT,
                                                            const int* __restrict__ off,
                                                            float* __restrict__ cost,
                                                            float* __restrict__ gamma,
                                                            float* __restrict__ geds2,
                                                            int Ns) {
    __shared__ float sST[24960];      // sS[192*65] | sT[192*65]; later reused as 96*193 bounce
    __shared__ float part[32 * 193];  // matvec partials
    __shared__ float u[MAXN];
    __shared__ float v[MAXN];
    __shared__ float sqS[MAXN];
    __shared__ float sqT[MAXN];
    __shared__ __align__(16) float virt[64];
    __shared__ float wsum[16];

    int p = blockIdx.x;
    int tid = threadIdx.x;
    int ti = tid & 31, tj = tid >> 5;
    int n = lenS[p], m = lenT[p];
    int offs = off[p], offt = off[PAIRS + p];
    float* sS = sST;
    float* sT = sST + 12480;

    if (tid < 64) {
        float vv = vraw[tid];
        float ss = vv * vv;
#pragma unroll
        for (int d = 32; d > 0; d >>= 1) ss += __shfl_xor(ss, d, 64);
        virt[tid] = vv / fmaxf(sqrtf(ss), 1e-12f);
    }
    __syncthreads();

    for (int t = tid; t < 192 * 16; t += 1024) {
        int r = t >> 4, q = t & 15;
        int gi = offs + r; if (gi > Ns - 1) gi = Ns - 1;
        float4 vv = ((const float4*)embS)[(size_t)gi * 16 + q];
        float* d = sS + r * 65 + q * 4;
        d[0] = vv.x; d[1] = vv.y; d[2] = vv.z; d[3] = vv.w;
    }
    for (int t = tid; t < 192 * 16; t += 1024) {
        int j = t >> 4, q = t & 15;
        float4 vv;
        if (j < m) vv = ((const float4*)embT)[(size_t)(offt + j) * 16 + q];
        else       vv = ((const float4*)virt)[q];
        float* d = sT + j * 65 + q * 4;
        d[0] = vv.x; d[1] = vv.y; d[2] = vv.z; d[3] = vv.w;
    }
    __syncthreads();

    if (tid < 192) {
        float s = 0.f;
#pragma unroll
        for (int k = 0; k < 64; k++) { float a = sS[tid * 65 + k]; s = fmaf(a, a, s); }
        sqS[tid] = s;
    } else if (tid < 384) {
        int j = tid - 192;
        float s = 0.f;
#pragma unroll
        for (int k = 0; k < 64; k++) { float a = sT[j * 65 + k]; s = fmaf(a, a, s); }
        sqT[j] = s;
    }
    __syncthreads();

    // ---- phase A: 6x6 cost tile in registers ----
    float kt[6][6];
#pragma unroll
    for (int r = 0; r < 6; r++)
#pragma unroll
        for (int c = 0; c < 6; c++) kt[r][c] = 0.f;

    int ib = ti * 6, jb = tj * 6;
    for (int k = 0; k < 64; k++) {
        float sv[6], tv[6];
#pragma unroll
        for (int r = 0; r < 6; r++) sv[r] = sS[(ib + r) * 65 + k];
#pragma unroll
        for (int c = 0; c < 6; c++) tv[c] = sT[(jb + c) * 65 + k];
#pragma unroll
        for (int r = 0; r < 6; r++)
#pragma unroll
            for (int c = 0; c < 6; c++) kt[r][c] = fmaf(sv[r], tv[c], kt[r][c]);
    }
#pragma unroll
    for (int r = 0; r < 6; r++) {
        int i = ib + r;
        bool rv = i < n;
        float sqi = sqS[i];
#pragma unroll
        for (int c = 0; c < 6; c++) {
            int j = jb + c;
            float cd = sqrtf(fmaxf(sqi + sqT[j] - 2.f * kt[r][c], 1e-12f));
            bool cv = j < n;
            kt[r][c] = (rv && cv) ? cd : ((!rv && !cv) ? 0.f : 1000.f);
        }
    }

    // ---- write cost via LDS bounce (2 row-halves), coalesced HBM stores ----
    float* bounce = sST;
    float* cp = cost + (size_t)p * MAXN * MAXN;
    for (int h = 0; h < 2; h++) {
        __syncthreads();
        if ((ti >> 4) == h) {
            int rb = ib - 96 * h;
#pragma unroll
            for (int r = 0; r < 6; r++)
#pragma unroll
                for (int c = 0; c < 6; c++)
                    bounce[(rb + r) * 193 + jb + c] = kt[r][c];
        }
        __syncthreads();
        for (int q = 0; q < 18; q++) {
            int el = q * 1024 + tid;
            int row = el / 192, col = el - row * 192;
            cp[(size_t)(96 * h + row) * 192 + col] = bounce[row * 193 + col];
        }
    }

    // ---- K = exp(-10*cost) in registers ----
#pragma unroll
    for (int r = 0; r < 6; r++)
#pragma unroll
        for (int c = 0; c < 6; c++) kt[r][c] = expf(-10.f * kt[r][c]);

    if (tid < MAXN) u[tid] = 1.f / 192.f;

    // ---- 8 Sinkhorn iterations, partials through part[] ----
    for (int it = 0; it < 8; it++) {
        __syncthreads();
        {
            float ur[6];
#pragma unroll
            for (int r = 0; r < 6; r++) ur[r] = u[ib + r];
#pragma unroll
            for (int c = 0; c < 6; c++) {
                float s = 0.f;
#pragma unroll
                for (int r = 0; r < 6; r++) s = fmaf(kt[r][c], ur[r], s);
                part[ti * 193 + jb + c] = s;
            }
        }
        __syncthreads();
        if (tid < MAXN) {
            float s = 0.f;
#pragma unroll
            for (int q = 0; q < 32; q++) s += part[q * 193 + tid];
            v[tid] = 1.f / s;
        }
        __syncthreads();
        {
            float vc[6];
#pragma unroll
            for (int c = 0; c < 6; c++) vc[c] = v[jb + c];
#pragma unroll
            for (int r = 0; r < 6; r++) {
                float s = 0.f;
#pragma unroll
                for (int c = 0; c < 6; c++) s = fmaf(kt[r][c], vc[c], s);
                part[tj * 193 + ib + r] = s;
            }
        }
        __syncthreads();
        if (tid < MAXN) {
            float s = 0.f;
#pragma unroll
            for (int q = 0; q < 32; q++) s += part[q * 193 + tid];
            u[tid] = 1.f / s;
        }
    }
    __syncthreads();

    // ---- gamma + geds ----
    float ur[6], vc[6];
#pragma unroll
    for (int r = 0; r < 6; r++) ur[r] = u[ib + r];
#pragma unroll
    for (int c = 0; c < 6; c++) vc[c] = v[jb + c];

    float acc = 0.f;
#pragma unroll
    for (int r = 0; r < 6; r++)
#pragma unroll
        for (int c = 0; c < 6; c++) {
            float kk = kt[r][c];
            float g = ur[r] * kk * vc[c];
            if (kk > 0.f) acc = fmaf(g, -0.1f * logf(kk), acc);
        }
#pragma unroll
    for (int d = 32; d > 0; d >>= 1) acc += __shfl_xor(acc, d, 64);
    if ((tid & 63) == 0) wsum[tid >> 6] = acc;

    float* gp = gamma + (size_t)p * MAXN * MAXN;
    for (int h = 0; h < 2; h++) {
        __syncthreads();
        if ((ti >> 4) == h) {
            int rb = ib - 96 * h;
#pragma unroll
            for (int r = 0; r < 6; r++)
#pragma unroll
                for (int c = 0; c < 6; c++)
                    bounce[(rb + r) * 193 + jb + c] = ur[r] * kt[r][c] * vc[c];
        }
        __syncthreads();
        for (int q = 0; q < 18; q++) {
            int el = q * 1024 + tid;
            int row = el / 192, col = el - row * 192;
            gp[(size_t)(96 * h + row) * 192 + col] = bounce[row * 193 + col];
        }
    }
    if (tid == 0) {
        float s = 0.f;
        for (int q = 0; q < 16; q++) s += wsum[q];
        geds2[p] = s / (float)(n + m);
    }
}

extern "C" void kernel_launch(void* const* d_in, const int* in_sizes, int n_in,
                              void* d_out, int out_size, void* d_ws, size_t ws_size,
                              hipStream_t stream) {
    const float* x_s     = (const float*)d_in[0];
    const float* x_t     = (const float*)d_in[1];
    const float* W_rel0  = (const float*)d_in[2];
    const float* b_rel0  = (const float*)d_in[3];
    const float* W_root0 = (const float*)d_in[4];
    const float* W_rel1  = (const float*)d_in[5];
    const float* b_rel1  = (const float*)d_in[6];
    const float* W_root1 = (const float*)d_in[7];
    const float* W_e     = (const float*)d_in[8];
    const float* b_e     = (const float*)d_in[9];
    const float* virt    = (const float*)d_in[10];
    const int*   ei_s    = (const int*)d_in[11];
    const int*   ei_t    = (const int*)d_in[12];
    const int*   len_s   = (const int*)d_in[13];
    const int*   len_t   = (const int*)d_in[14];

    int Ns = in_sizes[0] / 32;
    int Nt = in_sizes[1] / 32;
    int Es = in_sizes[11] / 2;
    int Et = in_sizes[12] / 2;
    int Ntot = Ns + Nt;
    int Etot = Es + Et;

    // ---- workspace layout ----
    char* w = (char*)d_ws;
    int* off  = (int*)w;              w += 1024 * 4;
    int* bsum = (int*)w;              w += 256 * 4;
    int* rs   = (int*)w;              w += (size_t)Ntot * 4;
    int* cur  = (int*)w;              w += (size_t)Ntot * 4;
    int* src  = (int*)w;              w += (size_t)Etot * 4;
    w = (char*)(((size_t)w + 255) & ~(size_t)255);
    float* agg = (float*)w;           w += (size_t)Ntot * 64 * 4;  // gather out; later emb
    float* h1  = (float*)w;           w += (size_t)Ntot * 64 * 4;
    float* h2  = (float*)w;           w += (size_t)Ntot * 64 * 4;

    float* out_gamma = (float*)d_out;
    float* out_cost  = out_gamma + (size_t)PAIRS * MAXN * MAXN;
    float* out_geds  = out_cost + (size_t)PAIRS * MAXN * MAXN;

    offsets_kernel<<<1, PAIRS, 0, stream>>>(len_s, len_t, off);

    // ---- combined CSR build (multi-block scan: ~10 µs vs 240 µs single-block) ----
    hipMemsetAsync(rs, 0, (size_t)Ntot * 4, stream);
    count2_kernel<<<(Etot + 255) / 256, 256, 0, stream>>>(ei_s, ei_t, rs, Es, Et, Ns);
    int nb = (Ntot + 1023) / 1024;
    scan1_kernel<<<nb, 256, 0, stream>>>(rs, bsum, Ntot);
    scan2_kernel<<<1, 256, 0, stream>>>(bsum, nb);
    scan3_kernel<<<(Ntot + 255) / 256, 256, 0, stream>>>(rs, bsum, cur, Ntot);
    fill2_kernel<<<(Etot + 255) / 256, 256, 0, stream>>>(ei_s, ei_t, cur, src, Es, Et, Ns);

    int gblk = (Ntot + 63) / 64;

    // ---- combined GNN ----
    gather_kernel<32><<<(int)(((long long)Ntot * 32 + 255) / 256), 256, 0, stream>>>(
        x_s, x_t, Ns, rs, cur, src, agg, Ntot);
    lin_gemm_kernel<32><<<gblk, 256, 0, stream>>>(
        agg, x_s, x_t, Ns, W_rel0, b_rel0, W_root0, h1, Ntot);
    gather_kernel<64><<<(int)(((long long)Ntot * 64 + 255) / 256), 256, 0, stream>>>(
        h1, h1 + (size_t)Ns * 64, Ns, rs, cur, src, agg, Ntot);
    lin_gemm_kernel<64><<<gblk, 256, 0, stream>>>(
        agg, h1, h1, Ntot + 1, W_rel1, b_rel1, W_root1, h2, Ntot);  // h1 combined: split never hit
    emb_gemm_kernel<<<gblk, 256, 0, stream>>>(
        x_s, x_t, Ns, h1, h2, W_e, b_e, agg, Ntot);  // emb -> agg (S rows then T rows)

    // ---- fused cost + sinkhorn ----
    cost_sink_kernel<<<PAIRS, 1024, 0, stream>>>(
        agg, agg + (size_t)Ns * 64, virt, len_s, len_t, off,
        out_cost, out_gamma, out_geds, Ns);
}